// Round 19
// baseline (234.884 us; speedup 1.0000x reference)
//
#include <hip/hip_runtime.h>
#include <hip/hip_fp16.h>
#include <cstdint>
#include <cstddef>

// ---------------------------------------------------------------------------
// out[b] = Re{ sum_i FFT3(Bs*k1_i) * FFT3(Bs*k2_i) },  b<16, i<30,
// vol (64,32,32), Bs = fftshift(B). Harness compares REAL PART only
// (out_size = 1,048,576 float32). With z = Bs*k1 + j*Bs*k2:
//   Re(out)(w) = 1/4 * ( Im S(w) + Im S(-w) ),  S = sum_i FFT3(z_i)^2.
//
// Primary path (workspace-backed):
//   kpack    : k1,k2 -> kch fp16 [i][d0][d1][d2] (7.9MB, L2-resident)
//   kfft2d_ws: block = (b, i-triple, d0-quad), 3-iter barrier-free pipeline;
//              grid 2560 -> ~4 waves/SIMD resident (vs 2.5 at 6-i blocks),
//              hiding the FFT dependency-chain stalls.
//   kacc64   : per (b,d1f,ig): four-step FFT64 along d0, ImS accum,
//              atomicAdd tmp += ImS/4
//   ksym     : out[w] = tmp[w] + tmp[-w]
// Fallback (ws too small): EXACT round-6 fused kernel (proven PASS).
// ---------------------------------------------------------------------------

typedef unsigned int u32x4 __attribute__((ext_vector_type(4)));

__host__ __device__ constexpr float twc(int k) {
  switch (k & 31) {
    case 0: return 1.0f;        case 1: return 0.98078528f;
    case 2: return 0.92387953f; case 3: return 0.83146961f;
    case 4: return 0.70710678f; case 5: return 0.55557023f;
    case 6: return 0.38268343f; case 7: return 0.19509032f;
    case 8: return 0.0f;        case 9: return -0.19509032f;
    case 10: return -0.38268343f; case 11: return -0.55557023f;
    case 12: return -0.70710678f; case 13: return -0.83146961f;
    case 14: return -0.92387953f; case 15: return -0.98078528f;
    default: return 0.0f;
  }
}
__host__ __device__ constexpr float tws(int k) {
  switch (k & 31) {
    case 0: return 0.0f;        case 1: return 0.19509032f;
    case 2: return 0.38268343f; case 3: return 0.55557023f;
    case 4: return 0.70710678f; case 5: return 0.83146961f;
    case 6: return 0.92387953f; case 7: return 0.98078528f;
    case 8: return 1.0f;        case 9: return 0.98078528f;
    case 10: return 0.92387953f; case 11: return 0.83146961f;
    case 12: return 0.70710678f; case 13: return 0.55557023f;
    case 14: return 0.38268343f; case 15: return 0.19509032f;
    default: return 0.0f;
  }
}

constexpr int brN(int x, int bits) {
  int r = 0;
  for (int b = 0; b < bits; ++b) { r = (r << 1) | (x & 1); x >>= 1; }
  return r;
}

template <int N>
__device__ __forceinline__ void fftN(float* xr, float* xi) {
#pragma unroll
  for (int len = 2; len <= N; len <<= 1) {
    const int half = len >> 1;
    const int step = 32 / len;
#pragma unroll
    for (int g = 0; g < N; g += len) {
#pragma unroll
      for (int j = 0; j < half; ++j) {
        const float c = twc(j * step), s = tws(j * step);
        const int lo = g + j, hi = g + j + half;
        float vr = xr[hi] * c + xi[hi] * s;
        float vi = xi[hi] * c - xr[hi] * s;
        float ur = xr[lo], ui = xi[lo];
        xr[lo] = ur + vr; xi[lo] = ui + vi;
        xr[hi] = ur - vr; xi[hi] = ui - vi;
      }
    }
  }
}

__device__ __forceinline__ unsigned h2u(__half2 h) {
  union { __half2 h; unsigned u; } c; c.h = h; return c.u;
}
__device__ __forceinline__ float2 u2f2(unsigned u) {
  union { unsigned u; __half2 h; } c; c.u = u; return __half22float2(c.h);
}

// ---- zero helper (guarded) ------------------------------------------------
__global__ __launch_bounds__(256) void kzero(float4* __restrict__ o, int n4) {
  int i = blockIdx.x * 256 + threadIdx.x;
  if (i < n4) o[i] = make_float4(0.f, 0.f, 0.f, 0.f);
}

// ===========================================================================
// PRIMARY PATH (workspace-backed)
// ===========================================================================

// ---- pack k1,k2 (64,32,32,30) -> kch fp16 [i][d0][d1][d2] -----------------
__global__ __launch_bounds__(256) void kpack(const float* __restrict__ k1,
                                             const float* __restrict__ k2,
                                             unsigned* __restrict__ kch) {
  int d0 = blockIdx.x >> 5, d1 = blockIdx.x & 31;
  __shared__ unsigned s[960];  // [d2][i] packed half2
  int base = (d0 * 32 + d1) * 960;
  for (int u = threadIdx.x; u < 960; u += 256)
    s[u] = h2u(__float22half2_rn(make_float2(k1[base + u], k2[base + u])));
  __syncthreads();
  for (int w = threadIdx.x; w < 960; w += 256) {
    int i = w >> 5, d2 = w & 31;
    kch[((size_t)(i * 64 + d0) * 32 + d1) * 32 + d2] = s[d2 * 30 + i];
  }
}

// ---- stage 1: block = (b, i-triple ig, d0-quad q2); 3-iter pipeline -------
// BARRIER-FREE (slab transpose is wave-local). Grid: cb*10*16 x 128 thr.
__global__ __launch_bounds__(128, 4) void kfft2d_ws(
    const float* __restrict__ B, const unsigned* __restrict__ kch,
    __half2* __restrict__ Z, int b0) {
  __shared__ __half2 Ms[4][32 * 33];   // 4224B/slab, per-slab private region

  const int t = threadIdx.x;
  const int q2 = blockIdx.x & 15;         // d0 quad
  const int r = blockIdx.x >> 4;
  const int ig = r % 10;                  // i-triple: i = ig*3 .. ig*3+2
  const int bl = r / 10;                  // chunk-local batch
  const int b = b0 + bl;

  const int s = t >> 5;                   // slab 0..3
  const int lc = t & 31;                  // phase A: d2 col; phase B: d1f row
  const int n0 = (q2 << 2) | s;

  // ---- B operand: i-invariant; load ONCE per block -------------------------
  float breg[32];
  {
    const int sn0 = (n0 + 32) & 63;
    const float* bp = B + ((size_t)b << 16) + (sn0 << 10);
    const int sc = (lc + 16) & 31;                 // fftshift d2
#pragma unroll
    for (int n1 = 0; n1 < 32; ++n1)
      breg[n1] = bp[(((n1 + 16) & 31) << 5) | sc]; // fftshift d1
  }

  // kch base for i = ig*3, this d0; per-i stride = 65536 dwords
  const unsigned* kc0 = kch + (((size_t)(ig * 3) << 6 | n0) << 10);
  unsigned kreg[32];
#pragma unroll
  for (int n1 = 0; n1 < 32; ++n1)
    kreg[n1] = kc0[(n1 << 5) | lc];

  for (int ii = 0; ii < 3; ++ii) {
    float xr[32], xi[32];

    // ---- consume kreg: build + bit-rev ----
#pragma unroll
    for (int n1 = 0; n1 < 32; ++n1) {
      float2 kv = u2f2(kreg[n1]);
      xr[brN(n1, 5)] = breg[n1] * kv.x;
      xi[brN(n1, 5)] = breg[n1] * kv.y;
    }

    // ---- issue k loads for i+1 NOW; latency hides under fftA+LDS+fftB ----
    if (ii < 2) {
      const unsigned* kn = kc0 + ((size_t)(ii + 1) << 16);
#pragma unroll
      for (int n1 = 0; n1 < 32; ++n1)
        kreg[n1] = kn[(n1 << 5) | lc];
    }

    // ---- FFT along d1 (registers) -> LDS transpose (wave-local, no bar) ----
    fftN<32>(xr, xi);
#pragma unroll
    for (int u = 0; u < 32; ++u)
      Ms[s][u * 33 + lc] = __float22half2_rn(make_float2(xr[u], xi[u]));

    // ---- FFT along d2 (registers), write Z ----
    {
      const int rr = lc;                           // d1f row
#pragma unroll
      for (int j = 0; j < 32; ++j) {
        float2 q = __half22float2(Ms[s][rr * 33 + j]);
        xr[brN(j, 5)] = q.x;
        xi[brN(j, 5)] = q.y;
      }
      fftN<32>(xr, xi);

      const int v = bl * 30 + ig * 3 + ii;
      __half2* zrow = Z + (((size_t)v << 16) | (n0 << 10) | (rr << 5));
      u32x4* z4 = reinterpret_cast<u32x4*>(zrow);
#pragma unroll
      for (int k = 0; k < 8; ++k) {
        __half2 h0 =
            __float22half2_rn(make_float2(xr[4 * k + 0], xi[4 * k + 0]));
        __half2 h1 =
            __float22half2_rn(make_float2(xr[4 * k + 1], xi[4 * k + 1]));
        __half2 h2 =
            __float22half2_rn(make_float2(xr[4 * k + 2], xi[4 * k + 2]));
        __half2 h3 =
            __float22half2_rn(make_float2(xr[4 * k + 3], xi[4 * k + 3]));
        u32x4 pk = {h2u(h0), h2u(h1), h2u(h2), h2u(h3)};
        z4[k] = pk;
      }
    }
    // no barrier: next iteration's writes are program-ordered after reads
  }
}

// ---- stage 2: per (b, d1f, ig): FFT64 along d0, ImS partial accum ---------
__global__ __launch_bounds__(256) void kacc64(const __half2* __restrict__ Z,
                                              float* __restrict__ tmp,
                                              int b0, int cb) {
  __shared__ float Ar[64 * 33], Ai[64 * 33];
  __shared__ float Br[64 * 33], Bi[64 * 33];
  __shared__ float W64c[64], W64s[64];

  const int t = threadIdx.x;
  const int d1 = blockIdx.x & 31;
  const int r = blockIdx.x >> 5;
  const int bl = r % cb;
  const int ig = r / cb;
  const int b = b0 + bl;
  const int i0g = ig * 8;
  const int i1g = (i0g + 8) < 30 ? (i0g + 8) : 30;

  if (t < 64) {
    float sv, cv;
    __sincosf(6.283185307179586f / 64.0f * (float)t, &sv, &cv);
    W64c[t] = cv; W64s[t] = sv;
  }
  __syncthreads();

  const int qc = t >> 5;    // phase 1: q ; phase 2: c
  const int d2 = t & 31;

  float acc[8];
#pragma unroll
  for (int a = 0; a < 8; ++a) acc[a] = 0.f;

  for (int i = i0g; i < i1g; ++i) {
    const int v = bl * 30 + i;
    // Z natural layout: [v][d0][d1][d2]; plane for fixed d1
    const __half2* zv = Z + (((size_t)v << 16) | (d1 << 5));
#pragma unroll
    for (int j = 0; j < 8; ++j) {
      int f = (j << 8) | t;
      int rd0 = f >> 5, rc = f & 31;
      float2 w = __half22float2(zv[((size_t)rd0 << 10) | rc]);
      Ar[rd0 * 33 + rc] = w.x;
      Ai[rd0 * 33 + rc] = w.y;
    }
    __syncthreads();

    // phase 1: G[c] = FFT8_p( z[q+8p] ); H[c] = G[c]*W64^{qc}; store B[8c+q]
    {
      float xr[8], xi[8];
#pragma unroll
      for (int u = 0; u < 8; ++u) {
        int n0 = qc + (brN(u, 3) << 3);
        xr[u] = Ar[n0 * 33 + d2]; xi[u] = Ai[n0 * 33 + d2];
      }
      fftN<8>(xr, xi);
#pragma unroll
      for (int c = 0; c < 8; ++c) {
        int m = (qc * c) & 63;
        float wc = W64c[m], ws = W64s[m];
        float hr = xr[c] * wc + xi[c] * ws;
        float hi = xi[c] * wc - xr[c] * ws;
        int q2 = (c << 3) | qc;
        Br[q2 * 33 + d2] = hr; Bi[q2 * 33 + d2] = hi;
      }
    }
    __syncthreads();

    // phase 2: Zf[c+8a] = FFT8_q( H[q][c] ); acc[a] += 2*Re*Im
    {
      float xr[8], xi[8];
#pragma unroll
      for (int u = 0; u < 8; ++u) {
        int q2 = (qc << 3) | brN(u, 3);
        xr[u] = Br[q2 * 33 + d2]; xi[u] = Bi[q2 * 33 + d2];
      }
      fftN<8>(xr, xi);
#pragma unroll
      for (int a = 0; a < 8; ++a)
        acc[a] += 2.0f * xr[a] * xi[a];
    }
    __syncthreads();
  }

#pragma unroll
  for (int a = 0; a < 8; ++a) {
    int d0f = qc + (a << 3);
    size_t off = ((size_t)(b << 6 | d0f) << 10) | (d1 << 5) | d2;
    atomicAdd(&tmp[off], 0.25f * acc[a]);
  }
}

// ---- final: out[w] = tmp[w] + tmp[-w] -------------------------------------
__global__ __launch_bounds__(256) void ksym(const float* __restrict__ tmp,
                                            float* __restrict__ out,
                                            int out_size) {
  int idx = blockIdx.x * 256 + threadIdx.x;
  if (idx >= out_size || idx >= 16 * 65536) return;
  int d2 = idx & 31, d1 = (idx >> 5) & 31, d0 = (idx >> 10) & 63, b = idx >> 16;
  int n = (b << 16) | (((64 - d0) & 63) << 10) | (((32 - d1) & 31) << 5) |
          ((32 - d2) & 31);
  out[idx] = tmp[idx] + tmp[n];
}

// ===========================================================================
// FALLBACK PATH: exact round-6 fused kernel (proven PASS)
// ===========================================================================
__global__ __launch_bounds__(256) void kfused(const float* __restrict__ B,
                                              const float* __restrict__ k1,
                                              const float* __restrict__ k2,
                                              float* __restrict__ out,
                                              int out_size) {
  __shared__ float Lr[4][32 * 33];
  __shared__ float Li[4][32 * 33];
  __shared__ float W64c[64], W64s[64];

  const int t = threadIdx.x;
  const int bid = blockIdx.x;
  const int b = bid & 15;
  const int iq = (bid >> 4) & 3;
  const int ns = bid >> 6;
  const int i0 = iq * 8;
  const int ni = (iq == 3) ? 6 : 8;
  const int k0base = ns * 8;

  if (t < 64) {
    float sv, cv;
    __sincosf(6.283185307179586f / 64.0f * (float)t, &sv, &cv);
    W64c[t] = cv; W64s[t] = sv;
  }
  __syncthreads();

  const int g = t >> 6;
  const int bc = t & 31;
  const int hh = (t >> 5) & 1;
  const int fs = t >> 5;
  const int fr = t & 31;
  const int w1 = t >> 5;
  const int w2 = t & 31;

  const float* Bb = B + ((size_t)b << 16);

  float Sig[8][4];
#pragma unroll
  for (int kg = 0; kg < 8; ++kg)
#pragma unroll
    for (int q = 0; q < 4; ++q) Sig[kg][q] = 0.f;

  for (int ii = 0; ii < ni; ++ii) {
    const int i = i0 + ii;

    float Zr[8][4], Zi[8][4];
#pragma unroll
    for (int kg = 0; kg < 8; ++kg)
#pragma unroll
      for (int q = 0; q < 4; ++q) { Zr[kg][q] = 0.f; Zi[kg][q] = 0.f; }

    for (int it = 0; it < 16; ++it) {
      const int n0 = (it << 2) | g;
      {
        const int sn0 = (n0 + 32) & 63;
        const float* bp = Bb + (sn0 << 10);
        const int sc = (bc + 16) & 31;
#pragma unroll
        for (int v = 0; v < 16; ++v) {
          const int n1 = (hh << 4) | v;
          float bv = bp[(((n1 + 16) & 31) << 5) | sc];
          int ke = (((n0 << 10) | (n1 << 5) | bc) * 30) + i;
          Lr[g][n1 * 33 + bc] = bv * k1[ke];
          Li[g][n1 * 33 + bc] = bv * k2[ke];
        }
      }
      __syncthreads();

      if (t < 128) {
        float xr[32], xi[32];
#pragma unroll
        for (int u = 0; u < 32; ++u) {
          int p = fr * 33 + brN(u, 5);
          xr[u] = Lr[fs][p]; xi[u] = Li[fs][p];
        }
        fftN<32>(xr, xi);
#pragma unroll
        for (int u = 0; u < 32; ++u) {
          int p = fr * 33 + u;
          Lr[fs][p] = xr[u]; Li[fs][p] = xi[u];
        }
      }
      __syncthreads();

      if (t < 128) {
        float xr[32], xi[32];
#pragma unroll
        for (int u = 0; u < 32; ++u) {
          int p = brN(u, 5) * 33 + fr;
          xr[u] = Lr[fs][p]; xi[u] = Li[fs][p];
        }
        fftN<32>(xr, xi);
#pragma unroll
        for (int u = 0; u < 32; ++u) {
          int p = u * 33 + fr;
          Lr[fs][p] = xr[u]; Li[fs][p] = xi[u];
        }
      }
      __syncthreads();

#pragma unroll 1
      for (int sq = 0; sq < 4; ++sq) {
        const int n0s = (it << 2) | sq;
        const int dm = n0s & 63;
        float yr[4], yi[4];
#pragma unroll
        for (int q = 0; q < 4; ++q) {
          int p = (w1 + (q << 3)) * 33 + w2;
          yr[q] = Lr[sq][p]; yi[q] = Li[sq][p];
        }
        int m = (k0base * n0s) & 63;
#pragma unroll
        for (int kg = 0; kg < 8; ++kg) {
          float c = W64c[m], sn = W64s[m];
#pragma unroll
          for (int q = 0; q < 4; ++q) {
            Zr[kg][q] += yr[q] * c + yi[q] * sn;
            Zi[kg][q] += yi[q] * c - yr[q] * sn;
          }
          m = (m + dm) & 63;
        }
      }
      __syncthreads();
    }

#pragma unroll
    for (int kg = 0; kg < 8; ++kg)
#pragma unroll
      for (int q = 0; q < 4; ++q)
        Sig[kg][q] += 2.0f * Zr[kg][q] * Zi[kg][q];
  }

#pragma unroll
  for (int kg = 0; kg < 8; ++kg) {
    const int k0 = k0base + kg;
    const int nk0 = (64 - k0) & 63;
#pragma unroll
    for (int q = 0; q < 4; ++q) {
      const int r1 = w1 + (q << 3);
      const float v = Sig[kg][q] * 0.25f;
      const int nr1 = (32 - r1) & 31;
      const int nw2 = (32 - w2) & 31;
      int off = (((b << 6) | k0) << 10) | (r1 << 5) | w2;
      int noff = (((b << 6) | nk0) << 10) | (nr1 << 5) | nw2;
      if (off < out_size) atomicAdd(&out[off], v);
      if (noff < out_size) atomicAdd(&out[noff], v);
    }
  }
}

// ---------------------------------------------------------------------------
extern "C" void kernel_launch(void* const* d_in, const int* in_sizes, int n_in,
                              void* d_out, int out_size, void* d_ws,
                              size_t ws_size, hipStream_t stream) {
  const float* B = (const float*)d_in[0];
  const float* k1 = (const float*)d_in[1];
  const float* k2 = (const float*)d_in[2];
  (void)in_sizes; (void)n_in;

  const size_t tmpB = 4ull << 20;            // 4 MB ImS/4 accumulator
  const size_t Z1 = 30ull * 65536 * 4;       // 7,864,320 B per batch (fp16)
  const size_t kcB = 30ull * 65536 * 4;      // 7,864,320 B packed fp16 k

  int nbcap = 0;
  if (ws_size >= tmpB + kcB + Z1)
    nbcap = (int)((ws_size - tmpB - kcB) / Z1);

  if (nbcap >= 1) {
    // -------- primary workspace path --------
    char* ws = (char*)d_ws;
    float* tmp = (float*)ws;
    unsigned* kch = (unsigned*)(ws + tmpB);
    __half2* Z = (__half2*)(ws + tmpB + kcB);
    int nb = nbcap > 16 ? 16 : nbcap;

    kzero<<<(out_size / 4 + 255) / 256, 256, 0, stream>>>((float4*)tmp,
                                                          out_size / 4);
    kpack<<<2048, 256, 0, stream>>>(k1, k2, kch);

    for (int b0 = 0; b0 < 16; b0 += nb) {
      int cb = (16 - b0) < nb ? (16 - b0) : nb;
      kfft2d_ws<<<cb * 160, 128, 0, stream>>>(B, kch, Z, b0);
      kacc64<<<cb * 32 * 4, 256, 0, stream>>>(Z, tmp, b0, cb);
    }

    ksym<<<(out_size + 255) / 256, 256, 0, stream>>>(tmp, (float*)d_out,
                                                     out_size);
  } else {
    // -------- proven zero-workspace fallback (round-6, bit-exact) --------
    int n4 = out_size >> 2;
    int zb = (n4 + 255) >> 8;
    if (zb > 0) kzero<<<zb, 256, 0, stream>>>((float4*)d_out, n4);
    kfused<<<512, 256, 0, stream>>>(B, k1, k2, (float*)d_out, out_size);
  }
}

// Round 20
// 102.969 us; speedup vs baseline: 2.2811x; 2.2811x over previous
//
#include <hip/hip_runtime.h>
#include <hip/hip_fp16.h>
#include <cstdint>
#include <cstddef>

// ---------------------------------------------------------------------------
// out[b] = Re{ sum_i FFT3(Bs*k1_i) * FFT3(Bs*k2_i) },  b<16, i<30,
// vol (64,32,32), Bs = fftshift(B). Harness compares REAL PART only
// (out_size = 1,048,576 float32). With z = Bs*k1 + j*Bs*k2:
//   Re(out)(w) = 1/4 * ( Im S(w) + Im S(-w) ),  S = sum_i FFT3(z_i)^2.
//
// Primary path (workspace-backed):
//   kpack    : k1,k2 -> kch fp16 [i][d0][d1][d2] (7.9MB, L2-resident)
//   kfft2d_ws: block = (b, i-triple, d0-quad), 3-iter barrier-free pipeline,
//              grid 2560 (10 blocks/CU). NOTE: plain __launch_bounds__(128) —
//              the (128,4) min-waves hint forced VGPR=64 and spilled
//              breg/kreg to scratch (238MB fetch, 3x regression, round 19).
//   kacc64   : per (b,d1f,ig): four-step FFT64 along d0, ImS accum,
//              atomicAdd tmp += ImS/4
//   ksym     : out[w] = tmp[w] + tmp[-w]
// Fallback (ws too small): EXACT round-6 fused kernel (proven PASS).
// ---------------------------------------------------------------------------

typedef unsigned int u32x4 __attribute__((ext_vector_type(4)));

__host__ __device__ constexpr float twc(int k) {
  switch (k & 31) {
    case 0: return 1.0f;        case 1: return 0.98078528f;
    case 2: return 0.92387953f; case 3: return 0.83146961f;
    case 4: return 0.70710678f; case 5: return 0.55557023f;
    case 6: return 0.38268343f; case 7: return 0.19509032f;
    case 8: return 0.0f;        case 9: return -0.19509032f;
    case 10: return -0.38268343f; case 11: return -0.55557023f;
    case 12: return -0.70710678f; case 13: return -0.83146961f;
    case 14: return -0.92387953f; case 15: return -0.98078528f;
    default: return 0.0f;
  }
}
__host__ __device__ constexpr float tws(int k) {
  switch (k & 31) {
    case 0: return 0.0f;        case 1: return 0.19509032f;
    case 2: return 0.38268343f; case 3: return 0.55557023f;
    case 4: return 0.70710678f; case 5: return 0.83146961f;
    case 6: return 0.92387953f; case 7: return 0.98078528f;
    case 8: return 1.0f;        case 9: return 0.98078528f;
    case 10: return 0.92387953f; case 11: return 0.83146961f;
    case 12: return 0.70710678f; case 13: return 0.55557023f;
    case 14: return 0.38268343f; case 15: return 0.19509032f;
    default: return 0.0f;
  }
}

constexpr int brN(int x, int bits) {
  int r = 0;
  for (int b = 0; b < bits; ++b) { r = (r << 1) | (x & 1); x >>= 1; }
  return r;
}

template <int N>
__device__ __forceinline__ void fftN(float* xr, float* xi) {
#pragma unroll
  for (int len = 2; len <= N; len <<= 1) {
    const int half = len >> 1;
    const int step = 32 / len;
#pragma unroll
    for (int g = 0; g < N; g += len) {
#pragma unroll
      for (int j = 0; j < half; ++j) {
        const float c = twc(j * step), s = tws(j * step);
        const int lo = g + j, hi = g + j + half;
        float vr = xr[hi] * c + xi[hi] * s;
        float vi = xi[hi] * c - xr[hi] * s;
        float ur = xr[lo], ui = xi[lo];
        xr[lo] = ur + vr; xi[lo] = ui + vi;
        xr[hi] = ur - vr; xi[hi] = ui - vi;
      }
    }
  }
}

__device__ __forceinline__ unsigned h2u(__half2 h) {
  union { __half2 h; unsigned u; } c; c.h = h; return c.u;
}
__device__ __forceinline__ float2 u2f2(unsigned u) {
  union { unsigned u; __half2 h; } c; c.u = u; return __half22float2(c.h);
}

// ---- zero helper (guarded) ------------------------------------------------
__global__ __launch_bounds__(256) void kzero(float4* __restrict__ o, int n4) {
  int i = blockIdx.x * 256 + threadIdx.x;
  if (i < n4) o[i] = make_float4(0.f, 0.f, 0.f, 0.f);
}

// ===========================================================================
// PRIMARY PATH (workspace-backed)
// ===========================================================================

// ---- pack k1,k2 (64,32,32,30) -> kch fp16 [i][d0][d1][d2] -----------------
__global__ __launch_bounds__(256) void kpack(const float* __restrict__ k1,
                                             const float* __restrict__ k2,
                                             unsigned* __restrict__ kch) {
  int d0 = blockIdx.x >> 5, d1 = blockIdx.x & 31;
  __shared__ unsigned s[960];  // [d2][i] packed half2
  int base = (d0 * 32 + d1) * 960;
  for (int u = threadIdx.x; u < 960; u += 256)
    s[u] = h2u(__float22half2_rn(make_float2(k1[base + u], k2[base + u])));
  __syncthreads();
  for (int w = threadIdx.x; w < 960; w += 256) {
    int i = w >> 5, d2 = w & 31;
    kch[((size_t)(i * 64 + d0) * 32 + d1) * 32 + d2] = s[d2 * 30 + i];
  }
}

// ---- stage 1: block = (b, i-triple ig, d0-quad q2); 3-iter pipeline -------
// BARRIER-FREE (slab transpose is wave-local). Grid: cb*10*16 x 128 thr.
__global__ __launch_bounds__(128) void kfft2d_ws(
    const float* __restrict__ B, const unsigned* __restrict__ kch,
    __half2* __restrict__ Z, int b0) {
  __shared__ __half2 Ms[4][32 * 33];   // 4224B/slab, per-slab private region

  const int t = threadIdx.x;
  const int q2 = blockIdx.x & 15;         // d0 quad
  const int r = blockIdx.x >> 4;
  const int ig = r % 10;                  // i-triple: i = ig*3 .. ig*3+2
  const int bl = r / 10;                  // chunk-local batch
  const int b = b0 + bl;

  const int s = t >> 5;                   // slab 0..3
  const int lc = t & 31;                  // phase A: d2 col; phase B: d1f row
  const int n0 = (q2 << 2) | s;

  // ---- B operand: i-invariant; load ONCE per block -------------------------
  float breg[32];
  {
    const int sn0 = (n0 + 32) & 63;
    const float* bp = B + ((size_t)b << 16) + (sn0 << 10);
    const int sc = (lc + 16) & 31;                 // fftshift d2
#pragma unroll
    for (int n1 = 0; n1 < 32; ++n1)
      breg[n1] = bp[(((n1 + 16) & 31) << 5) | sc]; // fftshift d1
  }

  // kch base for i = ig*3, this d0; per-i stride = 65536 dwords
  const unsigned* kc0 = kch + (((size_t)(ig * 3) << 6 | n0) << 10);
  unsigned kreg[32];
#pragma unroll
  for (int n1 = 0; n1 < 32; ++n1)
    kreg[n1] = kc0[(n1 << 5) | lc];

  for (int ii = 0; ii < 3; ++ii) {
    float xr[32], xi[32];

    // ---- consume kreg: build + bit-rev ----
#pragma unroll
    for (int n1 = 0; n1 < 32; ++n1) {
      float2 kv = u2f2(kreg[n1]);
      xr[brN(n1, 5)] = breg[n1] * kv.x;
      xi[brN(n1, 5)] = breg[n1] * kv.y;
    }

    // ---- issue k loads for i+1 NOW; latency hides under fftA+LDS+fftB ----
    if (ii < 2) {
      const unsigned* kn = kc0 + ((size_t)(ii + 1) << 16);
#pragma unroll
      for (int n1 = 0; n1 < 32; ++n1)
        kreg[n1] = kn[(n1 << 5) | lc];
    }

    // ---- FFT along d1 (registers) -> LDS transpose (wave-local, no bar) ----
    fftN<32>(xr, xi);
#pragma unroll
    for (int u = 0; u < 32; ++u)
      Ms[s][u * 33 + lc] = __float22half2_rn(make_float2(xr[u], xi[u]));

    // ---- FFT along d2 (registers), write Z ----
    {
      const int rr = lc;                           // d1f row
#pragma unroll
      for (int j = 0; j < 32; ++j) {
        float2 q = __half22float2(Ms[s][rr * 33 + j]);
        xr[brN(j, 5)] = q.x;
        xi[brN(j, 5)] = q.y;
      }
      fftN<32>(xr, xi);

      const int v = bl * 30 + ig * 3 + ii;
      __half2* zrow = Z + (((size_t)v << 16) | (n0 << 10) | (rr << 5));
      u32x4* z4 = reinterpret_cast<u32x4*>(zrow);
#pragma unroll
      for (int k = 0; k < 8; ++k) {
        __half2 h0 =
            __float22half2_rn(make_float2(xr[4 * k + 0], xi[4 * k + 0]));
        __half2 h1 =
            __float22half2_rn(make_float2(xr[4 * k + 1], xi[4 * k + 1]));
        __half2 h2 =
            __float22half2_rn(make_float2(xr[4 * k + 2], xi[4 * k + 2]));
        __half2 h3 =
            __float22half2_rn(make_float2(xr[4 * k + 3], xi[4 * k + 3]));
        u32x4 pk = {h2u(h0), h2u(h1), h2u(h2), h2u(h3)};
        z4[k] = pk;
      }
    }
    // no barrier: next iteration's writes are program-ordered after reads
  }
}

// ---- stage 2: per (b, d1f, ig): FFT64 along d0, ImS partial accum ---------
__global__ __launch_bounds__(256) void kacc64(const __half2* __restrict__ Z,
                                              float* __restrict__ tmp,
                                              int b0, int cb) {
  __shared__ float Ar[64 * 33], Ai[64 * 33];
  __shared__ float Br[64 * 33], Bi[64 * 33];
  __shared__ float W64c[64], W64s[64];

  const int t = threadIdx.x;
  const int d1 = blockIdx.x & 31;
  const int r = blockIdx.x >> 5;
  const int bl = r % cb;
  const int ig = r / cb;
  const int b = b0 + bl;
  const int i0g = ig * 8;
  const int i1g = (i0g + 8) < 30 ? (i0g + 8) : 30;

  if (t < 64) {
    float sv, cv;
    __sincosf(6.283185307179586f / 64.0f * (float)t, &sv, &cv);
    W64c[t] = cv; W64s[t] = sv;
  }
  __syncthreads();

  const int qc = t >> 5;    // phase 1: q ; phase 2: c
  const int d2 = t & 31;

  float acc[8];
#pragma unroll
  for (int a = 0; a < 8; ++a) acc[a] = 0.f;

  for (int i = i0g; i < i1g; ++i) {
    const int v = bl * 30 + i;
    // Z natural layout: [v][d0][d1][d2]; plane for fixed d1
    const __half2* zv = Z + (((size_t)v << 16) | (d1 << 5));
#pragma unroll
    for (int j = 0; j < 8; ++j) {
      int f = (j << 8) | t;
      int rd0 = f >> 5, rc = f & 31;
      float2 w = __half22float2(zv[((size_t)rd0 << 10) | rc]);
      Ar[rd0 * 33 + rc] = w.x;
      Ai[rd0 * 33 + rc] = w.y;
    }
    __syncthreads();

    // phase 1: G[c] = FFT8_p( z[q+8p] ); H[c] = G[c]*W64^{qc}; store B[8c+q]
    {
      float xr[8], xi[8];
#pragma unroll
      for (int u = 0; u < 8; ++u) {
        int n0 = qc + (brN(u, 3) << 3);
        xr[u] = Ar[n0 * 33 + d2]; xi[u] = Ai[n0 * 33 + d2];
      }
      fftN<8>(xr, xi);
#pragma unroll
      for (int c = 0; c < 8; ++c) {
        int m = (qc * c) & 63;
        float wc = W64c[m], ws = W64s[m];
        float hr = xr[c] * wc + xi[c] * ws;
        float hi = xi[c] * wc - xr[c] * ws;
        int q2 = (c << 3) | qc;
        Br[q2 * 33 + d2] = hr; Bi[q2 * 33 + d2] = hi;
      }
    }
    __syncthreads();

    // phase 2: Zf[c+8a] = FFT8_q( H[q][c] ); acc[a] += 2*Re*Im
    {
      float xr[8], xi[8];
#pragma unroll
      for (int u = 0; u < 8; ++u) {
        int q2 = (qc << 3) | brN(u, 3);
        xr[u] = Br[q2 * 33 + d2]; xi[u] = Bi[q2 * 33 + d2];
      }
      fftN<8>(xr, xi);
#pragma unroll
      for (int a = 0; a < 8; ++a)
        acc[a] += 2.0f * xr[a] * xi[a];
    }
    __syncthreads();
  }

#pragma unroll
  for (int a = 0; a < 8; ++a) {
    int d0f = qc + (a << 3);
    size_t off = ((size_t)(b << 6 | d0f) << 10) | (d1 << 5) | d2;
    atomicAdd(&tmp[off], 0.25f * acc[a]);
  }
}

// ---- final: out[w] = tmp[w] + tmp[-w] -------------------------------------
__global__ __launch_bounds__(256) void ksym(const float* __restrict__ tmp,
                                            float* __restrict__ out,
                                            int out_size) {
  int idx = blockIdx.x * 256 + threadIdx.x;
  if (idx >= out_size || idx >= 16 * 65536) return;
  int d2 = idx & 31, d1 = (idx >> 5) & 31, d0 = (idx >> 10) & 63, b = idx >> 16;
  int n = (b << 16) | (((64 - d0) & 63) << 10) | (((32 - d1) & 31) << 5) |
          ((32 - d2) & 31);
  out[idx] = tmp[idx] + tmp[n];
}

// ===========================================================================
// FALLBACK PATH: exact round-6 fused kernel (proven PASS)
// ===========================================================================
__global__ __launch_bounds__(256) void kfused(const float* __restrict__ B,
                                              const float* __restrict__ k1,
                                              const float* __restrict__ k2,
                                              float* __restrict__ out,
                                              int out_size) {
  __shared__ float Lr[4][32 * 33];
  __shared__ float Li[4][32 * 33];
  __shared__ float W64c[64], W64s[64];

  const int t = threadIdx.x;
  const int bid = blockIdx.x;
  const int b = bid & 15;
  const int iq = (bid >> 4) & 3;
  const int ns = bid >> 6;
  const int i0 = iq * 8;
  const int ni = (iq == 3) ? 6 : 8;
  const int k0base = ns * 8;

  if (t < 64) {
    float sv, cv;
    __sincosf(6.283185307179586f / 64.0f * (float)t, &sv, &cv);
    W64c[t] = cv; W64s[t] = sv;
  }
  __syncthreads();

  const int g = t >> 6;
  const int bc = t & 31;
  const int hh = (t >> 5) & 1;
  const int fs = t >> 5;
  const int fr = t & 31;
  const int w1 = t >> 5;
  const int w2 = t & 31;

  const float* Bb = B + ((size_t)b << 16);

  float Sig[8][4];
#pragma unroll
  for (int kg = 0; kg < 8; ++kg)
#pragma unroll
    for (int q = 0; q < 4; ++q) Sig[kg][q] = 0.f;

  for (int ii = 0; ii < ni; ++ii) {
    const int i = i0 + ii;

    float Zr[8][4], Zi[8][4];
#pragma unroll
    for (int kg = 0; kg < 8; ++kg)
#pragma unroll
      for (int q = 0; q < 4; ++q) { Zr[kg][q] = 0.f; Zi[kg][q] = 0.f; }

    for (int it = 0; it < 16; ++it) {
      const int n0 = (it << 2) | g;
      {
        const int sn0 = (n0 + 32) & 63;
        const float* bp = Bb + (sn0 << 10);
        const int sc = (bc + 16) & 31;
#pragma unroll
        for (int v = 0; v < 16; ++v) {
          const int n1 = (hh << 4) | v;
          float bv = bp[(((n1 + 16) & 31) << 5) | sc];
          int ke = (((n0 << 10) | (n1 << 5) | bc) * 30) + i;
          Lr[g][n1 * 33 + bc] = bv * k1[ke];
          Li[g][n1 * 33 + bc] = bv * k2[ke];
        }
      }
      __syncthreads();

      if (t < 128) {
        float xr[32], xi[32];
#pragma unroll
        for (int u = 0; u < 32; ++u) {
          int p = fr * 33 + brN(u, 5);
          xr[u] = Lr[fs][p]; xi[u] = Li[fs][p];
        }
        fftN<32>(xr, xi);
#pragma unroll
        for (int u = 0; u < 32; ++u) {
          int p = fr * 33 + u;
          Lr[fs][p] = xr[u]; Li[fs][p] = xi[u];
        }
      }
      __syncthreads();

      if (t < 128) {
        float xr[32], xi[32];
#pragma unroll
        for (int u = 0; u < 32; ++u) {
          int p = brN(u, 5) * 33 + fr;
          xr[u] = Lr[fs][p]; xi[u] = Li[fs][p];
        }
        fftN<32>(xr, xi);
#pragma unroll
        for (int u = 0; u < 32; ++u) {
          int p = u * 33 + fr;
          Lr[fs][p] = xr[u]; Li[fs][p] = xi[u];
        }
      }
      __syncthreads();

#pragma unroll 1
      for (int sq = 0; sq < 4; ++sq) {
        const int n0s = (it << 2) | sq;
        const int dm = n0s & 63;
        float yr[4], yi[4];
#pragma unroll
        for (int q = 0; q < 4; ++q) {
          int p = (w1 + (q << 3)) * 33 + w2;
          yr[q] = Lr[sq][p]; yi[q] = Li[sq][p];
        }
        int m = (k0base * n0s) & 63;
#pragma unroll
        for (int kg = 0; kg < 8; ++kg) {
          float c = W64c[m], sn = W64s[m];
#pragma unroll
          for (int q = 0; q < 4; ++q) {
            Zr[kg][q] += yr[q] * c + yi[q] * sn;
            Zi[kg][q] += yi[q] * c - yr[q] * sn;
          }
          m = (m + dm) & 63;
        }
      }
      __syncthreads();
    }

#pragma unroll
    for (int kg = 0; kg < 8; ++kg)
#pragma unroll
      for (int q = 0; q < 4; ++q)
        Sig[kg][q] += 2.0f * Zr[kg][q] * Zi[kg][q];
  }

#pragma unroll
  for (int kg = 0; kg < 8; ++kg) {
    const int k0 = k0base + kg;
    const int nk0 = (64 - k0) & 63;
#pragma unroll
    for (int q = 0; q < 4; ++q) {
      const int r1 = w1 + (q << 3);
      const float v = Sig[kg][q] * 0.25f;
      const int nr1 = (32 - r1) & 31;
      const int nw2 = (32 - w2) & 31;
      int off = (((b << 6) | k0) << 10) | (r1 << 5) | w2;
      int noff = (((b << 6) | nk0) << 10) | (nr1 << 5) | nw2;
      if (off < out_size) atomicAdd(&out[off], v);
      if (noff < out_size) atomicAdd(&out[noff], v);
    }
  }
}

// ---------------------------------------------------------------------------
extern "C" void kernel_launch(void* const* d_in, const int* in_sizes, int n_in,
                              void* d_out, int out_size, void* d_ws,
                              size_t ws_size, hipStream_t stream) {
  const float* B = (const float*)d_in[0];
  const float* k1 = (const float*)d_in[1];
  const float* k2 = (const float*)d_in[2];
  (void)in_sizes; (void)n_in;

  const size_t tmpB = 4ull << 20;            // 4 MB ImS/4 accumulator
  const size_t Z1 = 30ull * 65536 * 4;       // 7,864,320 B per batch (fp16)
  const size_t kcB = 30ull * 65536 * 4;      // 7,864,320 B packed fp16 k

  int nbcap = 0;
  if (ws_size >= tmpB + kcB + Z1)
    nbcap = (int)((ws_size - tmpB - kcB) / Z1);

  if (nbcap >= 1) {
    // -------- primary workspace path --------
    char* ws = (char*)d_ws;
    float* tmp = (float*)ws;
    unsigned* kch = (unsigned*)(ws + tmpB);
    __half2* Z = (__half2*)(ws + tmpB + kcB);
    int nb = nbcap > 16 ? 16 : nbcap;

    kzero<<<(out_size / 4 + 255) / 256, 256, 0, stream>>>((float4*)tmp,
                                                          out_size / 4);
    kpack<<<2048, 256, 0, stream>>>(k1, k2, kch);

    for (int b0 = 0; b0 < 16; b0 += nb) {
      int cb = (16 - b0) < nb ? (16 - b0) : nb;
      kfft2d_ws<<<cb * 160, 128, 0, stream>>>(B, kch, Z, b0);
      kacc64<<<cb * 32 * 4, 256, 0, stream>>>(Z, tmp, b0, cb);
    }

    ksym<<<(out_size + 255) / 256, 256, 0, stream>>>(tmp, (float*)d_out,
                                                     out_size);
  } else {
    // -------- proven zero-workspace fallback (round-6, bit-exact) --------
    int n4 = out_size >> 2;
    int zb = (n4 + 255) >> 8;
    if (zb > 0) kzero<<<zb, 256, 0, stream>>>((float4*)d_out, n4);
    kfused<<<512, 256, 0, stream>>>(B, k1, k2, (float*)d_out, out_size);
  }
}

// Round 21
// 102.857 us; speedup vs baseline: 2.2836x; 1.0011x over previous
//
#include <hip/hip_runtime.h>
#include <hip/hip_fp16.h>
#include <cstdint>
#include <cstddef>

// ---------------------------------------------------------------------------
// out[b] = Re{ sum_i FFT3(Bs*k1_i) * FFT3(Bs*k2_i) },  b<16, i<30,
// vol (64,32,32), Bs = fftshift(B). Harness compares REAL PART only
// (out_size = 1,048,576 float32). With z = Bs*k1 + j*Bs*k2:
//   Re(out)(w) = 1/4 * ( Im S(w) + Im S(-w) ),  S = sum_i FFT3(z_i)^2.
//
// Primary path (workspace-backed):
//   kpack    : k1,k2 -> kch fp16 [i][d0][d1][d2] (7.9MB, L2-resident)
//   kfft2d_ws: block = (b, i-triple, d0-OCTET), 256 thr / 8 slabs / 33.8KB,
//              3-iter barrier-free pipeline. 4 waves/block decouples
//              waves-per-CU from the ~3-block residency cap observed in
//              r13-r20 (128-thr blocks pinned occupancy at ~18%).
//   kacc64   : per (b,d1f,ig): four-step FFT64 along d0, ImS accum,
//              atomicAdd tmp += ImS/4
//   ksym     : out[w] = tmp[w] + tmp[-w]
// Fallback (ws too small): EXACT round-6 fused kernel (proven PASS).
// ---------------------------------------------------------------------------

typedef unsigned int u32x4 __attribute__((ext_vector_type(4)));

__host__ __device__ constexpr float twc(int k) {
  switch (k & 31) {
    case 0: return 1.0f;        case 1: return 0.98078528f;
    case 2: return 0.92387953f; case 3: return 0.83146961f;
    case 4: return 0.70710678f; case 5: return 0.55557023f;
    case 6: return 0.38268343f; case 7: return 0.19509032f;
    case 8: return 0.0f;        case 9: return -0.19509032f;
    case 10: return -0.38268343f; case 11: return -0.55557023f;
    case 12: return -0.70710678f; case 13: return -0.83146961f;
    case 14: return -0.92387953f; case 15: return -0.98078528f;
    default: return 0.0f;
  }
}
__host__ __device__ constexpr float tws(int k) {
  switch (k & 31) {
    case 0: return 0.0f;        case 1: return 0.19509032f;
    case 2: return 0.38268343f; case 3: return 0.55557023f;
    case 4: return 0.70710678f; case 5: return 0.83146961f;
    case 6: return 0.92387953f; case 7: return 0.98078528f;
    case 8: return 1.0f;        case 9: return 0.98078528f;
    case 10: return 0.92387953f; case 11: return 0.83146961f;
    case 12: return 0.70710678f; case 13: return 0.55557023f;
    case 14: return 0.38268343f; case 15: return 0.19509032f;
    default: return 0.0f;
  }
}

constexpr int brN(int x, int bits) {
  int r = 0;
  for (int b = 0; b < bits; ++b) { r = (r << 1) | (x & 1); x >>= 1; }
  return r;
}

template <int N>
__device__ __forceinline__ void fftN(float* xr, float* xi) {
#pragma unroll
  for (int len = 2; len <= N; len <<= 1) {
    const int half = len >> 1;
    const int step = 32 / len;
#pragma unroll
    for (int g = 0; g < N; g += len) {
#pragma unroll
      for (int j = 0; j < half; ++j) {
        const float c = twc(j * step), s = tws(j * step);
        const int lo = g + j, hi = g + j + half;
        float vr = xr[hi] * c + xi[hi] * s;
        float vi = xi[hi] * c - xr[hi] * s;
        float ur = xr[lo], ui = xi[lo];
        xr[lo] = ur + vr; xi[lo] = ui + vi;
        xr[hi] = ur - vr; xi[hi] = ui - vi;
      }
    }
  }
}

__device__ __forceinline__ unsigned h2u(__half2 h) {
  union { __half2 h; unsigned u; } c; c.h = h; return c.u;
}
__device__ __forceinline__ float2 u2f2(unsigned u) {
  union { unsigned u; __half2 h; } c; c.u = u; return __half22float2(c.h);
}

// ---- zero helper (guarded) ------------------------------------------------
__global__ __launch_bounds__(256) void kzero(float4* __restrict__ o, int n4) {
  int i = blockIdx.x * 256 + threadIdx.x;
  if (i < n4) o[i] = make_float4(0.f, 0.f, 0.f, 0.f);
}

// ===========================================================================
// PRIMARY PATH (workspace-backed)
// ===========================================================================

// ---- pack k1,k2 (64,32,32,30) -> kch fp16 [i][d0][d1][d2] -----------------
__global__ __launch_bounds__(256) void kpack(const float* __restrict__ k1,
                                             const float* __restrict__ k2,
                                             unsigned* __restrict__ kch) {
  int d0 = blockIdx.x >> 5, d1 = blockIdx.x & 31;
  __shared__ unsigned s[960];  // [d2][i] packed half2
  int base = (d0 * 32 + d1) * 960;
  for (int u = threadIdx.x; u < 960; u += 256)
    s[u] = h2u(__float22half2_rn(make_float2(k1[base + u], k2[base + u])));
  __syncthreads();
  for (int w = threadIdx.x; w < 960; w += 256) {
    int i = w >> 5, d2 = w & 31;
    kch[((size_t)(i * 64 + d0) * 32 + d1) * 32 + d2] = s[d2 * 30 + i];
  }
}

// ---- stage 1: block = (b, i-triple ig, d0-octet q3); 3-iter pipeline ------
// 256 thr / 8 slabs / 33.8KB LDS; BARRIER-FREE (slab transpose wave-local:
// slab s in wave s>>1). Grid: cb*10*8 x 256 thr.
__global__ __launch_bounds__(256) void kfft2d_ws(
    const float* __restrict__ B, const unsigned* __restrict__ kch,
    __half2* __restrict__ Z, int b0) {
  __shared__ __half2 Ms[8][32 * 33];   // 4224B/slab, per-slab private region

  const int t = threadIdx.x;
  const int q3 = blockIdx.x & 7;          // d0 octet
  const int r = blockIdx.x >> 3;
  const int ig = r % 10;                  // i-triple: i = ig*3 .. ig*3+2
  const int bl = r / 10;                  // chunk-local batch
  const int b = b0 + bl;

  const int s = t >> 5;                   // slab 0..7
  const int lc = t & 31;                  // phase A: d2 col; phase B: d1f row
  const int n0 = (q3 << 3) | s;

  // ---- B operand: i-invariant; load ONCE per block -------------------------
  float breg[32];
  {
    const int sn0 = (n0 + 32) & 63;
    const float* bp = B + ((size_t)b << 16) + (sn0 << 10);
    const int sc = (lc + 16) & 31;                 // fftshift d2
#pragma unroll
    for (int n1 = 0; n1 < 32; ++n1)
      breg[n1] = bp[(((n1 + 16) & 31) << 5) | sc]; // fftshift d1
  }

  // kch base for i = ig*3, this d0; per-i stride = 65536 dwords
  const unsigned* kc0 = kch + (((size_t)(ig * 3) << 6 | n0) << 10);
  unsigned kreg[32];
#pragma unroll
  for (int n1 = 0; n1 < 32; ++n1)
    kreg[n1] = kc0[(n1 << 5) | lc];

  for (int ii = 0; ii < 3; ++ii) {
    float xr[32], xi[32];

    // ---- consume kreg: build + bit-rev ----
#pragma unroll
    for (int n1 = 0; n1 < 32; ++n1) {
      float2 kv = u2f2(kreg[n1]);
      xr[brN(n1, 5)] = breg[n1] * kv.x;
      xi[brN(n1, 5)] = breg[n1] * kv.y;
    }

    // ---- issue k loads for i+1 NOW; latency hides under fftA+LDS+fftB ----
    if (ii < 2) {
      const unsigned* kn = kc0 + ((size_t)(ii + 1) << 16);
#pragma unroll
      for (int n1 = 0; n1 < 32; ++n1)
        kreg[n1] = kn[(n1 << 5) | lc];
    }

    // ---- FFT along d1 (registers) -> LDS transpose (wave-local, no bar) ----
    fftN<32>(xr, xi);
#pragma unroll
    for (int u = 0; u < 32; ++u)
      Ms[s][u * 33 + lc] = __float22half2_rn(make_float2(xr[u], xi[u]));

    // ---- FFT along d2 (registers), write Z ----
    {
      const int rr = lc;                           // d1f row
#pragma unroll
      for (int j = 0; j < 32; ++j) {
        float2 q = __half22float2(Ms[s][rr * 33 + j]);
        xr[brN(j, 5)] = q.x;
        xi[brN(j, 5)] = q.y;
      }
      fftN<32>(xr, xi);

      const int v = bl * 30 + ig * 3 + ii;
      __half2* zrow = Z + (((size_t)v << 16) | (n0 << 10) | (rr << 5));
      u32x4* z4 = reinterpret_cast<u32x4*>(zrow);
#pragma unroll
      for (int k = 0; k < 8; ++k) {
        __half2 h0 =
            __float22half2_rn(make_float2(xr[4 * k + 0], xi[4 * k + 0]));
        __half2 h1 =
            __float22half2_rn(make_float2(xr[4 * k + 1], xi[4 * k + 1]));
        __half2 h2 =
            __float22half2_rn(make_float2(xr[4 * k + 2], xi[4 * k + 2]));
        __half2 h3 =
            __float22half2_rn(make_float2(xr[4 * k + 3], xi[4 * k + 3]));
        u32x4 pk = {h2u(h0), h2u(h1), h2u(h2), h2u(h3)};
        z4[k] = pk;
      }
    }
    // no barrier: next iteration's writes are program-ordered after reads
  }
}

// ---- stage 2: per (b, d1f, ig): FFT64 along d0, ImS partial accum ---------
__global__ __launch_bounds__(256) void kacc64(const __half2* __restrict__ Z,
                                              float* __restrict__ tmp,
                                              int b0, int cb) {
  __shared__ float Ar[64 * 33], Ai[64 * 33];
  __shared__ float Br[64 * 33], Bi[64 * 33];
  __shared__ float W64c[64], W64s[64];

  const int t = threadIdx.x;
  const int d1 = blockIdx.x & 31;
  const int r = blockIdx.x >> 5;
  const int bl = r % cb;
  const int ig = r / cb;
  const int b = b0 + bl;
  const int i0g = ig * 8;
  const int i1g = (i0g + 8) < 30 ? (i0g + 8) : 30;

  if (t < 64) {
    float sv, cv;
    __sincosf(6.283185307179586f / 64.0f * (float)t, &sv, &cv);
    W64c[t] = cv; W64s[t] = sv;
  }
  __syncthreads();

  const int qc = t >> 5;    // phase 1: q ; phase 2: c
  const int d2 = t & 31;

  float acc[8];
#pragma unroll
  for (int a = 0; a < 8; ++a) acc[a] = 0.f;

  for (int i = i0g; i < i1g; ++i) {
    const int v = bl * 30 + i;
    // Z natural layout: [v][d0][d1][d2]; plane for fixed d1
    const __half2* zv = Z + (((size_t)v << 16) | (d1 << 5));
#pragma unroll
    for (int j = 0; j < 8; ++j) {
      int f = (j << 8) | t;
      int rd0 = f >> 5, rc = f & 31;
      float2 w = __half22float2(zv[((size_t)rd0 << 10) | rc]);
      Ar[rd0 * 33 + rc] = w.x;
      Ai[rd0 * 33 + rc] = w.y;
    }
    __syncthreads();

    // phase 1: G[c] = FFT8_p( z[q+8p] ); H[c] = G[c]*W64^{qc}; store B[8c+q]
    {
      float xr[8], xi[8];
#pragma unroll
      for (int u = 0; u < 8; ++u) {
        int n0 = qc + (brN(u, 3) << 3);
        xr[u] = Ar[n0 * 33 + d2]; xi[u] = Ai[n0 * 33 + d2];
      }
      fftN<8>(xr, xi);
#pragma unroll
      for (int c = 0; c < 8; ++c) {
        int m = (qc * c) & 63;
        float wc = W64c[m], ws = W64s[m];
        float hr = xr[c] * wc + xi[c] * ws;
        float hi = xi[c] * wc - xr[c] * ws;
        int q2 = (c << 3) | qc;
        Br[q2 * 33 + d2] = hr; Bi[q2 * 33 + d2] = hi;
      }
    }
    __syncthreads();

    // phase 2: Zf[c+8a] = FFT8_q( H[q][c] ); acc[a] += 2*Re*Im
    {
      float xr[8], xi[8];
#pragma unroll
      for (int u = 0; u < 8; ++u) {
        int q2 = (qc << 3) | brN(u, 3);
        xr[u] = Br[q2 * 33 + d2]; xi[u] = Bi[q2 * 33 + d2];
      }
      fftN<8>(xr, xi);
#pragma unroll
      for (int a = 0; a < 8; ++a)
        acc[a] += 2.0f * xr[a] * xi[a];
    }
    __syncthreads();
  }

#pragma unroll
  for (int a = 0; a < 8; ++a) {
    int d0f = qc + (a << 3);
    size_t off = ((size_t)(b << 6 | d0f) << 10) | (d1 << 5) | d2;
    atomicAdd(&tmp[off], 0.25f * acc[a]);
  }
}

// ---- final: out[w] = tmp[w] + tmp[-w] -------------------------------------
__global__ __launch_bounds__(256) void ksym(const float* __restrict__ tmp,
                                            float* __restrict__ out,
                                            int out_size) {
  int idx = blockIdx.x * 256 + threadIdx.x;
  if (idx >= out_size || idx >= 16 * 65536) return;
  int d2 = idx & 31, d1 = (idx >> 5) & 31, d0 = (idx >> 10) & 63, b = idx >> 16;
  int n = (b << 16) | (((64 - d0) & 63) << 10) | (((32 - d1) & 31) << 5) |
          ((32 - d2) & 31);
  out[idx] = tmp[idx] + tmp[n];
}

// ===========================================================================
// FALLBACK PATH: exact round-6 fused kernel (proven PASS)
// ===========================================================================
__global__ __launch_bounds__(256) void kfused(const float* __restrict__ B,
                                              const float* __restrict__ k1,
                                              const float* __restrict__ k2,
                                              float* __restrict__ out,
                                              int out_size) {
  __shared__ float Lr[4][32 * 33];
  __shared__ float Li[4][32 * 33];
  __shared__ float W64c[64], W64s[64];

  const int t = threadIdx.x;
  const int bid = blockIdx.x;
  const int b = bid & 15;
  const int iq = (bid >> 4) & 3;
  const int ns = bid >> 6;
  const int i0 = iq * 8;
  const int ni = (iq == 3) ? 6 : 8;
  const int k0base = ns * 8;

  if (t < 64) {
    float sv, cv;
    __sincosf(6.283185307179586f / 64.0f * (float)t, &sv, &cv);
    W64c[t] = cv; W64s[t] = sv;
  }
  __syncthreads();

  const int g = t >> 6;
  const int bc = t & 31;
  const int hh = (t >> 5) & 1;
  const int fs = t >> 5;
  const int fr = t & 31;
  const int w1 = t >> 5;
  const int w2 = t & 31;

  const float* Bb = B + ((size_t)b << 16);

  float Sig[8][4];
#pragma unroll
  for (int kg = 0; kg < 8; ++kg)
#pragma unroll
    for (int q = 0; q < 4; ++q) Sig[kg][q] = 0.f;

  for (int ii = 0; ii < ni; ++ii) {
    const int i = i0 + ii;

    float Zr[8][4], Zi[8][4];
#pragma unroll
    for (int kg = 0; kg < 8; ++kg)
#pragma unroll
      for (int q = 0; q < 4; ++q) { Zr[kg][q] = 0.f; Zi[kg][q] = 0.f; }

    for (int it = 0; it < 16; ++it) {
      const int n0 = (it << 2) | g;
      {
        const int sn0 = (n0 + 32) & 63;
        const float* bp = Bb + (sn0 << 10);
        const int sc = (bc + 16) & 31;
#pragma unroll
        for (int v = 0; v < 16; ++v) {
          const int n1 = (hh << 4) | v;
          float bv = bp[(((n1 + 16) & 31) << 5) | sc];
          int ke = (((n0 << 10) | (n1 << 5) | bc) * 30) + i;
          Lr[g][n1 * 33 + bc] = bv * k1[ke];
          Li[g][n1 * 33 + bc] = bv * k2[ke];
        }
      }
      __syncthreads();

      if (t < 128) {
        float xr[32], xi[32];
#pragma unroll
        for (int u = 0; u < 32; ++u) {
          int p = fr * 33 + brN(u, 5);
          xr[u] = Lr[fs][p]; xi[u] = Li[fs][p];
        }
        fftN<32>(xr, xi);
#pragma unroll
        for (int u = 0; u < 32; ++u) {
          int p = fr * 33 + u;
          Lr[fs][p] = xr[u]; Li[fs][p] = xi[u];
        }
      }
      __syncthreads();

      if (t < 128) {
        float xr[32], xi[32];
#pragma unroll
        for (int u = 0; u < 32; ++u) {
          int p = brN(u, 5) * 33 + fr;
          xr[u] = Lr[fs][p]; xi[u] = Li[fs][p];
        }
        fftN<32>(xr, xi);
#pragma unroll
        for (int u = 0; u < 32; ++u) {
          int p = u * 33 + fr;
          Lr[fs][p] = xr[u]; Li[fs][p] = xi[u];
        }
      }
      __syncthreads();

#pragma unroll 1
      for (int sq = 0; sq < 4; ++sq) {
        const int n0s = (it << 2) | sq;
        const int dm = n0s & 63;
        float yr[4], yi[4];
#pragma unroll
        for (int q = 0; q < 4; ++q) {
          int p = (w1 + (q << 3)) * 33 + w2;
          yr[q] = Lr[sq][p]; yi[q] = Li[sq][p];
        }
        int m = (k0base * n0s) & 63;
#pragma unroll
        for (int kg = 0; kg < 8; ++kg) {
          float c = W64c[m], sn = W64s[m];
#pragma unroll
          for (int q = 0; q < 4; ++q) {
            Zr[kg][q] += yr[q] * c + yi[q] * sn;
            Zi[kg][q] += yi[q] * c - yr[q] * sn;
          }
          m = (m + dm) & 63;
        }
      }
      __syncthreads();
    }

#pragma unroll
    for (int kg = 0; kg < 8; ++kg)
#pragma unroll
      for (int q = 0; q < 4; ++q)
        Sig[kg][q] += 2.0f * Zr[kg][q] * Zi[kg][q];
  }

#pragma unroll
  for (int kg = 0; kg < 8; ++kg) {
    const int k0 = k0base + kg;
    const int nk0 = (64 - k0) & 63;
#pragma unroll
    for (int q = 0; q < 4; ++q) {
      const int r1 = w1 + (q << 3);
      const float v = Sig[kg][q] * 0.25f;
      const int nr1 = (32 - r1) & 31;
      const int nw2 = (32 - w2) & 31;
      int off = (((b << 6) | k0) << 10) | (r1 << 5) | w2;
      int noff = (((b << 6) | nk0) << 10) | (nr1 << 5) | nw2;
      if (off < out_size) atomicAdd(&out[off], v);
      if (noff < out_size) atomicAdd(&out[noff], v);
    }
  }
}

// ---------------------------------------------------------------------------
extern "C" void kernel_launch(void* const* d_in, const int* in_sizes, int n_in,
                              void* d_out, int out_size, void* d_ws,
                              size_t ws_size, hipStream_t stream) {
  const float* B = (const float*)d_in[0];
  const float* k1 = (const float*)d_in[1];
  const float* k2 = (const float*)d_in[2];
  (void)in_sizes; (void)n_in;

  const size_t tmpB = 4ull << 20;            // 4 MB ImS/4 accumulator
  const size_t Z1 = 30ull * 65536 * 4;       // 7,864,320 B per batch (fp16)
  const size_t kcB = 30ull * 65536 * 4;      // 7,864,320 B packed fp16 k

  int nbcap = 0;
  if (ws_size >= tmpB + kcB + Z1)
    nbcap = (int)((ws_size - tmpB - kcB) / Z1);

  if (nbcap >= 1) {
    // -------- primary workspace path --------
    char* ws = (char*)d_ws;
    float* tmp = (float*)ws;
    unsigned* kch = (unsigned*)(ws + tmpB);
    __half2* Z = (__half2*)(ws + tmpB + kcB);
    int nb = nbcap > 16 ? 16 : nbcap;

    kzero<<<(out_size / 4 + 255) / 256, 256, 0, stream>>>((float4*)tmp,
                                                          out_size / 4);
    kpack<<<2048, 256, 0, stream>>>(k1, k2, kch);

    for (int b0 = 0; b0 < 16; b0 += nb) {
      int cb = (16 - b0) < nb ? (16 - b0) : nb;
      kfft2d_ws<<<cb * 80, 256, 0, stream>>>(B, kch, Z, b0);
      kacc64<<<cb * 32 * 4, 256, 0, stream>>>(Z, tmp, b0, cb);
    }

    ksym<<<(out_size + 255) / 256, 256, 0, stream>>>(tmp, (float*)d_out,
                                                     out_size);
  } else {
    // -------- proven zero-workspace fallback (round-6, bit-exact) --------
    int n4 = out_size >> 2;
    int zb = (n4 + 255) >> 8;
    if (zb > 0) kzero<<<zb, 256, 0, stream>>>((float4*)d_out, n4);
    kfused<<<512, 256, 0, stream>>>(B, k1, k2, (float*)d_out, out_size);
  }
}